// Round 1
// baseline (118.789 us; speedup 1.0000x reference)
//
#include <hip/hip_runtime.h>
#include <hip/hip_bf16.h>

#define NSEQ 2048
#define DD   64
#define HH   16
#define QT   128
#define KVB  64
#define NTHREADS 256
#define NKV  (NSEQ / KVB)

typedef __attribute__((ext_vector_type(4))) float  f4;
typedef __attribute__((ext_vector_type(4))) float  f32x4;
typedef __attribute__((ext_vector_type(8))) short  bf16x8;
typedef __attribute__((ext_vector_type(4))) unsigned short u16x4;

#define SCL   0.6005612043932249f   /* sqrt(0.25 * log2(e)) */
#define LOG2E 1.4426950408889634f
#define NEGBIG (-1.0e30f)

__device__ __forceinline__ unsigned short f2bf(float f) {
    unsigned int u = __float_as_uint(f);
    u += 0x7fffu + ((u >> 16) & 1u);
    return (unsigned short)(u >> 16);
}

template<int CTRL>
__device__ __forceinline__ float dppf(float x) {
    return __int_as_float(__builtin_amdgcn_update_dpp(
        0, __float_as_int(x), CTRL, 0xF, 0xF, true));
}
__device__ __forceinline__ float red_max16(float x) {
    x = fmaxf(x, dppf<0xB1>(x));    // quad_perm [1,0,3,2]  (xor 1)
    x = fmaxf(x, dppf<0x4E>(x));    // quad_perm [2,3,0,1]  (xor 2)
    x = fmaxf(x, dppf<0x141>(x));   // row_half_mirror      (pairs quads)
    x = fmaxf(x, dppf<0x140>(x));   // row_mirror           (pairs octets)
    return x;
}
__device__ __forceinline__ float red_sum16(float x) {
    x += dppf<0xB1>(x);
    x += dppf<0x4E>(x);
    x += dppf<0x141>(x);
    x += dppf<0x140>(x);
    return x;
}

#if defined(__has_builtin)
#if __has_builtin(__builtin_amdgcn_exp2f)
#define EXP2F __builtin_amdgcn_exp2f
#endif
#endif
#ifndef EXP2F
#define EXP2F exp2f
#endif

__global__ __launch_bounds__(NTHREADS)
void attend_kernel(const float* __restrict__ qg, const float* __restrict__ kg,
                   const float* __restrict__ vg, const int* __restrict__ maskg,
                   float* __restrict__ outg)
{
    __shared__ __align__(16) unsigned short Ks[KVB * DD];      // [j][d] swizzled
    __shared__ __align__(16) unsigned short Vt[DD * KVB];      // [d][j] swizzled
    __shared__ __align__(16) unsigned short Ps[4 * 32 * KVB];  // per-wave P
    __shared__ float bias_s[KVB];

    const int t    = threadIdx.x;
    const int w    = t >> 6;
    const int lane = t & 63;
    const int c    = lane & 15;
    const int g    = lane >> 4;
    const int cs8  = (c & 7) * 8;

    const int qtile = blockIdx.x;
    const int bh    = blockIdx.y;
    const int b     = bh / HH;

    const size_t base = (size_t)bh * NSEQ * DD;
    const float* kp = kg + base;
    const float* vp = vg + base;
    const int*   mp = maskg + b * NSEQ;

    // ---- Q fragments (held in registers, scaled into exp2-logit units)
    bf16x8 qf[2][2];
    #pragma unroll
    for (int rt = 0; rt < 2; ++rt) {
        const float* qp = qg + base + (size_t)(qtile*QT + w*32 + rt*16 + c) * DD;
        #pragma unroll
        for (int ks = 0; ks < 2; ++ks) {
            f4 a  = *(const f4*)(qp + ks*32 + g*8);
            f4 bb = *(const f4*)(qp + ks*32 + g*8 + 4);
            bf16x8 r;
            r[0] = (short)f2bf(a[0]*SCL);  r[1] = (short)f2bf(a[1]*SCL);
            r[2] = (short)f2bf(a[2]*SCL);  r[3] = (short)f2bf(a[3]*SCL);
            r[4] = (short)f2bf(bb[0]*SCL); r[5] = (short)f2bf(bb[1]*SCL);
            r[6] = (short)f2bf(bb[2]*SCL); r[7] = (short)f2bf(bb[3]*SCL);
            qf[rt][ks] = r;
        }
    }

    f32x4 acc[2][4];
    float m_run[2][4], l_run[2][4];
    #pragma unroll
    for (int rt = 0; rt < 2; ++rt) {
        #pragma unroll
        for (int dt = 0; dt < 4; ++dt) acc[rt][dt] = (f32x4){0.f,0.f,0.f,0.f};
        #pragma unroll
        for (int r = 0; r < 4; ++r) { m_run[rt][r] = NEGBIG; l_run[rt][r] = 0.f; }
    }

    const int sj = t >> 4;   // 0..15
    const int su = t & 15;

    f4 kr[4], vr[4];
    int mr[4];

    // ---- prologue: load tile 0 into registers
    #pragma unroll
    for (int i = 0; i < 4; ++i) {
        int j = i*16 + sj;
        kr[i] = *(const f4*)(kp + (size_t)j * DD + su*4);
        vr[i] = *(const f4*)(vp + (size_t)j * DD + su*4);
        mr[i] = mp[j];
    }

    for (int kt = 0; kt < NKV; ++kt) {
        __syncthreads();
        // ---- stage registers -> LDS (bf16), compute key bias in fp32
        #pragma unroll
        for (int i = 0; i < 4; ++i) {
            int j = i*16 + sj;
            float sq = kr[i][0]*kr[i][0] + kr[i][1]*kr[i][1]
                     + kr[i][2]*kr[i][2] + kr[i][3]*kr[i][3];
            sq = red_sum16(sq);
            if (su == 0) bias_s[j] = (mr[i] > 0) ? NEGBIG : -sq * LOG2E;
            u16x4 kk;
            kk[0] = f2bf(kr[i][0]*SCL); kk[1] = f2bf(kr[i][1]*SCL);
            kk[2] = f2bf(kr[i][2]*SCL); kk[3] = f2bf(kr[i][3]*SCL);
            *(u16x4*)&Ks[j*64 + ((su*4) ^ ((j&7)*8))] = kk;
            #pragma unroll
            for (int cc = 0; cc < 4; ++cc) {
                int d = su*4 + cc;
                Vt[d*64 + (j ^ ((d&7)*8))] = f2bf(vr[i][cc]);
            }
        }
        __syncthreads();

        // ---- prefetch next tile (latency hides under compute below)
        if (kt + 1 < NKV) {
            int j0 = (kt + 1) * KVB;
            #pragma unroll
            for (int i = 0; i < 4; ++i) {
                int j = i*16 + sj;
                kr[i] = *(const f4*)(kp + (size_t)(j0 + j) * DD + su*4);
                vr[i] = *(const f4*)(vp + (size_t)(j0 + j) * DD + su*4);
                mr[i] = mp[j0 + j];
            }
        }

        // ---- S = (scaled Q)(scaled K)^T   [exp2-logit units]
        float bv[4];
        #pragma unroll
        for (int jt = 0; jt < 4; ++jt) bv[jt] = bias_s[jt*16 + c];

        f32x4 s[2][4];
        #pragma unroll
        for (int jt = 0; jt < 4; ++jt) {
            int row = jt*16 + c;
            bf16x8 kb0 = *(const bf16x8*)&Ks[row*64 + ((g*8) ^ cs8)];
            bf16x8 kb1 = *(const bf16x8*)&Ks[row*64 + ((32 + g*8) ^ cs8)];
            #pragma unroll
            for (int rt = 0; rt < 2; ++rt) {
                f32x4 z = (f32x4){0.f,0.f,0.f,0.f};
                z = __builtin_amdgcn_mfma_f32_16x16x32_bf16(qf[rt][0], kb0, z, 0, 0, 0);
                z = __builtin_amdgcn_mfma_f32_16x16x32_bf16(qf[rt][1], kb1, z, 0, 0, 0);
                s[rt][jt] = z;
            }
        }

        // ---- online softmax; P -> LDS (bf16)
        #pragma unroll
        for (int rt = 0; rt < 2; ++rt) {
            #pragma unroll
            for (int r = 0; r < 4; ++r) {
                float s0 = s[rt][0][r] + bv[0];
                float s1 = s[rt][1][r] + bv[1];
                float s2 = s[rt][2][r] + bv[2];
                float s3 = s[rt][3][r] + bv[3];
                float mx = fmaxf(fmaxf(s0, s1), fmaxf(s2, s3));
                mx = red_max16(mx);
                float mn = fmaxf(m_run[rt][r], mx);
                float corr = EXP2F(m_run[rt][r] - mn);
                m_run[rt][r] = mn;
                float p0 = EXP2F(s0 - mn);
                float p1 = EXP2F(s1 - mn);
                float p2 = EXP2F(s2 - mn);
                float p3 = EXP2F(s3 - mn);
                float rs = red_sum16(p0 + p1 + p2 + p3);
                l_run[rt][r] = l_run[rt][r] * corr + rs;
                acc[rt][0][r] *= corr;
                acc[rt][1][r] *= corr;
                acc[rt][2][r] *= corr;
                acc[rt][3][r] *= corr;
                int lrow = rt*16 + g*4 + r;
                int prow = w*32 + lrow;
                int ls8  = (lrow & 7) * 8;
                Ps[prow*64 + ((     c) ^ ls8)] = f2bf(p0);
                Ps[prow*64 + ((16 + c) ^ ls8)] = f2bf(p1);
                Ps[prow*64 + ((32 + c) ^ ls8)] = f2bf(p2);
                Ps[prow*64 + ((48 + c) ^ ls8)] = f2bf(p3);
            }
        }

        asm volatile("s_waitcnt lgkmcnt(0)" ::: "memory");

        // ---- O += P V
        #pragma unroll
        for (int ks2 = 0; ks2 < 2; ++ks2) {
            bf16x8 pa0 = *(const bf16x8*)&Ps[(w*32 +  0 + c)*64 + ((ks2*32 + g*8) ^ cs8)];
            bf16x8 pa1 = *(const bf16x8*)&Ps[(w*32 + 16 + c)*64 + ((ks2*32 + g*8) ^ cs8)];
            #pragma unroll
            for (int dt = 0; dt < 4; ++dt) {
                bf16x8 vb = *(const bf16x8*)&Vt[(dt*16 + c)*64 + ((ks2*32 + g*8) ^ cs8)];
                acc[0][dt] = __builtin_amdgcn_mfma_f32_16x16x32_bf16(pa0, vb, acc[0][dt], 0, 0, 0);
                acc[1][dt] = __builtin_amdgcn_mfma_f32_16x16x32_bf16(pa1, vb, acc[1][dt], 0, 0, 0);
            }
        }
    }

    // ---- epilogue: normalize and store fp32
    #pragma unroll
    for (int rt = 0; rt < 2; ++rt) {
        #pragma unroll
        for (int r = 0; r < 4; ++r) {
            float inv = 1.0f / l_run[rt][r];
            float* op = outg + base + (size_t)(qtile*QT + w*32 + rt*16 + g*4 + r) * DD;
            #pragma unroll
            for (int dt = 0; dt < 4; ++dt)
                op[dt*16 + c] = acc[rt][dt][r] * inv;
        }
    }
}

extern "C" void kernel_launch(void* const* d_in, const int* in_sizes, int n_in,
                              void* d_out, int out_size, void* d_ws, size_t ws_size,
                              hipStream_t stream) {
    const float* q    = (const float*)d_in[0];
    const float* k    = (const float*)d_in[1];
    const float* v    = (const float*)d_in[2];
    const int*   mask = (const int*)d_in[3];
    float* out = (float*)d_out;
    dim3 grid(NSEQ / QT, 2 * HH);
    attend_kernel<<<grid, NTHREADS, 0, stream>>>(q, k, v, mask, out);
}

// Round 2
// 95.594 us; speedup vs baseline: 1.2426x; 1.2426x over previous
//
#include <hip/hip_runtime.h>
#include <hip/hip_bf16.h>

#define NSEQ 2048
#define DD   64
#define HH   16
#define QT   128
#define KVB  64
#define NKV  (NSEQ / KVB)
#define LS   72   /* LDS row stride in bf16 elements: bank phase 4*row%32 */

typedef __attribute__((ext_vector_type(4))) float  f4;
typedef __attribute__((ext_vector_type(4))) float  f32x4;
typedef __attribute__((ext_vector_type(8))) short  bf16x8;
typedef __attribute__((ext_vector_type(4))) unsigned short u16x4;

#define SCL   0.6005612043932249f   /* sqrt(0.25 * log2(e)) */
#define LOG2E 1.4426950408889634f
#define NEGBIG (-1.0e30f)

__device__ __forceinline__ unsigned short f2bf(float f) {
    unsigned int u = __float_as_uint(f);
    u += 0x7fffu + ((u >> 16) & 1u);
    return (unsigned short)(u >> 16);
}

template<int CTRL>
__device__ __forceinline__ float dppf(float x) {
    return __int_as_float(__builtin_amdgcn_update_dpp(
        0, __float_as_int(x), CTRL, 0xF, 0xF, true));
}
__device__ __forceinline__ float red_max16(float x) {
    x = fmaxf(x, dppf<0xB1>(x));
    x = fmaxf(x, dppf<0x4E>(x));
    x = fmaxf(x, dppf<0x141>(x));
    x = fmaxf(x, dppf<0x140>(x));
    return x;
}
__device__ __forceinline__ float red_sum16(float x) {
    x += dppf<0xB1>(x);
    x += dppf<0x4E>(x);
    x += dppf<0x141>(x);
    x += dppf<0x140>(x);
    return x;
}
__device__ __forceinline__ float red_sum4(float x) {
    x += dppf<0xB1>(x);
    x += dppf<0x4E>(x);
    return x;
}

#if defined(__has_builtin)
#if __has_builtin(__builtin_amdgcn_exp2f)
#define EXP2F __builtin_amdgcn_exp2f
#endif
#endif
#ifndef EXP2F
#define EXP2F exp2f
#endif

__device__ __forceinline__ bf16x8 cvt8(f4 a, f4 b, float scl) {
    bf16x8 r;
    r[0] = (short)f2bf(a[0]*scl); r[1] = (short)f2bf(a[1]*scl);
    r[2] = (short)f2bf(a[2]*scl); r[3] = (short)f2bf(a[3]*scl);
    r[4] = (short)f2bf(b[0]*scl); r[5] = (short)f2bf(b[1]*scl);
    r[6] = (short)f2bf(b[2]*scl); r[7] = (short)f2bf(b[3]*scl);
    return r;
}

__global__ __launch_bounds__(512, 4)
void attend_kernel(const float* __restrict__ qg, const float* __restrict__ kg,
                   const float* __restrict__ vg, const int* __restrict__ maskg,
                   float* __restrict__ outg)
{
    __shared__ __align__(16) unsigned short Ks[KVB * LS];  // [j][d], stride 72
    __shared__ __align__(16) unsigned short Vt[DD * LS];   // [d][j], stride 72, xor4 on j
    __shared__ __align__(16) unsigned short Ps[QT * LS];   // [qrow][j], stride 72
    __shared__ float bias_s[KVB];

    const int t    = threadIdx.x;
    const int w    = t >> 6;
    const int lane = t & 63;
    const int c    = lane & 15;
    const int g    = lane >> 4;

    // XCD-aware swizzle: all 16 q-tiles of one head land on one XCD
    const int p     = blockIdx.x;
    const int bh    = (p & 7) * 4 + ((p >> 3) >> 4);
    const int qtile = (p >> 3) & 15;
    const int b     = bh >> 4;   // HH = 16

    const size_t base = (size_t)bh * NSEQ * DD;
    const float* kp = kg + base;
    const float* vp = vg + base;
    const int*   mp = maskg + b * NSEQ;

    // ---- Q fragments: wave w owns q-rows qtile*128 + w*16 .. +15
    bf16x8 qf[2];
    {
        const float* qp = qg + base + (size_t)(qtile*QT + w*16 + c) * DD;
        #pragma unroll
        for (int ks = 0; ks < 2; ++ks) {
            f4 a  = *(const f4*)(qp + ks*32 + g*8);
            f4 bb = *(const f4*)(qp + ks*32 + g*8 + 4);
            qf[ks] = cvt8(a, bb, SCL);
        }
    }

    f32x4 acc[4];
    float m_run[4], l_run[4];
    #pragma unroll
    for (int dt = 0; dt < 4; ++dt) acc[dt] = (f32x4){0.f,0.f,0.f,0.f};
    #pragma unroll
    for (int r = 0; r < 4; ++r) { m_run[r] = NEGBIG; l_run[r] = 0.f; }

    // staging roles: waves 0-3 stage K + bias, waves 4-7 stage V
    const bool isK = (w < 4);
    const int  jK  = t >> 2;       // 0..63  (K row)
    const int  q4  = t & 3;        // 16-col quarter
    const int  u2  = t & 255;      // V-thread id
    const int  dq  = u2 & 15;      // d-quad
    const int  jq  = u2 >> 4;      // j-quad

    f4  st[4];
    int mreg = 0;

    // ---- prologue: tile 0 -> regs
    if (isK) {
        const float* src = kp + (size_t)jK * DD + q4*16;
        st[0] = ((const f4*)src)[0]; st[1] = ((const f4*)src)[1];
        st[2] = ((const f4*)src)[2]; st[3] = ((const f4*)src)[3];
        mreg = mp[jK];
    } else {
        #pragma unroll
        for (int i = 0; i < 4; ++i)
            st[i] = *(const f4*)(vp + (size_t)(jq*4 + i) * DD + dq*4);
    }

    for (int kt = 0; kt < NKV; ++kt) {
        __syncthreads();
        // ---- stage regs -> LDS
        if (isK) {
            float sq = 0.f;
            #pragma unroll
            for (int i = 0; i < 4; ++i)
                sq += st[i][0]*st[i][0] + st[i][1]*st[i][1]
                    + st[i][2]*st[i][2] + st[i][3]*st[i][3];
            sq = red_sum4(sq);
            if (q4 == 0) bias_s[jK] = (mreg > 0) ? NEGBIG : -sq * LOG2E;
            *(bf16x8*)&Ks[jK*LS + q4*16    ] = cvt8(st[0], st[1], SCL);
            *(bf16x8*)&Ks[jK*LS + q4*16 + 8] = cvt8(st[2], st[3], SCL);
        } else {
            #pragma unroll
            for (int cc = 0; cc < 4; ++cc) {
                int d = dq*4 + cc;
                u16x4 tv;
                tv[0] = f2bf(st[0][cc]); tv[1] = f2bf(st[1][cc]);
                tv[2] = f2bf(st[2][cc]); tv[3] = f2bf(st[3][cc]);
                *(u16x4*)&Vt[d*LS + ((jq*4) ^ (((d>>1)&7)*4))] = tv;
            }
        }
        __syncthreads();

        // ---- prefetch next tile (hides under compute)
        if (kt + 1 < NKV) {
            const int j0 = (kt + 1) * KVB;
            if (isK) {
                const float* src = kp + (size_t)(j0 + jK) * DD + q4*16;
                st[0] = ((const f4*)src)[0]; st[1] = ((const f4*)src)[1];
                st[2] = ((const f4*)src)[2]; st[3] = ((const f4*)src)[3];
                mreg = mp[j0 + jK];
            } else {
                #pragma unroll
                for (int i = 0; i < 4; ++i)
                    st[i] = *(const f4*)(vp + (size_t)(j0 + jq*4 + i) * DD + dq*4);
            }
        }

        // ---- S = (scaled Q)(scaled K)^T
        float bv[4];
        #pragma unroll
        for (int jt = 0; jt < 4; ++jt) bv[jt] = bias_s[jt*16 + c];

        f32x4 s[4];
        __builtin_amdgcn_s_setprio(1);
        #pragma unroll
        for (int jt = 0; jt < 4; ++jt) {
            int row = jt*16 + c;
            bf16x8 kb0 = *(const bf16x8*)&Ks[row*LS +      g*8];
            bf16x8 kb1 = *(const bf16x8*)&Ks[row*LS + 32 + g*8];
            f32x4 z = (f32x4){0.f,0.f,0.f,0.f};
            z = __builtin_amdgcn_mfma_f32_16x16x32_bf16(qf[0], kb0, z, 0, 0, 0);
            z = __builtin_amdgcn_mfma_f32_16x16x32_bf16(qf[1], kb1, z, 0, 0, 0);
            s[jt] = z;
        }
        __builtin_amdgcn_s_setprio(0);

        // ---- online softmax, P -> LDS
        #pragma unroll
        for (int r = 0; r < 4; ++r) {
            float s0 = s[0][r] + bv[0];
            float s1 = s[1][r] + bv[1];
            float s2 = s[2][r] + bv[2];
            float s3 = s[3][r] + bv[3];
            float mx = fmaxf(fmaxf(s0, s1), fmaxf(s2, s3));
            mx = red_max16(mx);
            float mn = fmaxf(m_run[r], mx);
            float corr = EXP2F(m_run[r] - mn);
            m_run[r] = mn;
            float p0 = EXP2F(s0 - mn);
            float p1 = EXP2F(s1 - mn);
            float p2 = EXP2F(s2 - mn);
            float p3 = EXP2F(s3 - mn);
            float rs = red_sum16(p0 + p1 + p2 + p3);
            l_run[r] = l_run[r] * corr + rs;
            acc[0][r] *= corr;
            acc[1][r] *= corr;
            acc[2][r] *= corr;
            acc[3][r] *= corr;
            int prow = w*16 + g*4 + r;
            Ps[prow*LS +      c] = f2bf(p0);
            Ps[prow*LS + 16 + c] = f2bf(p1);
            Ps[prow*LS + 32 + c] = f2bf(p2);
            Ps[prow*LS + 48 + c] = f2bf(p3);
        }

        asm volatile("s_waitcnt lgkmcnt(0)" ::: "memory");

        // ---- O += P V
        const int hx = (c >> 1) * 4;    // ((d>>1)&7)*4 with d = dt*16+c
        __builtin_amdgcn_s_setprio(1);
        #pragma unroll
        for (int ks2 = 0; ks2 < 2; ++ks2) {
            bf16x8 pa = *(const bf16x8*)&Ps[(w*16 + c)*LS + ks2*32 + g*8];
            #pragma unroll
            for (int dt = 0; dt < 4; ++dt) {
                int d = dt*16 + c;
                union { bf16x8 v8; u16x4 q[2]; } vb;
                vb.q[0] = *(const u16x4*)&Vt[d*LS + ((ks2*32 + g*8    ) ^ hx)];
                vb.q[1] = *(const u16x4*)&Vt[d*LS + ((ks2*32 + g*8 + 4) ^ hx)];
                acc[dt] = __builtin_amdgcn_mfma_f32_16x16x32_bf16(pa, vb.v8, acc[dt], 0, 0, 0);
            }
        }
        __builtin_amdgcn_s_setprio(0);
    }

    // ---- epilogue
    #pragma unroll
    for (int r = 0; r < 4; ++r) {
        float inv = 1.0f / l_run[r];
        float* op = outg + base + (size_t)(qtile*QT + w*16 + g*4 + r) * DD;
        #pragma unroll
        for (int dt = 0; dt < 4; ++dt)
            op[dt*16 + c] = acc[dt][r] * inv;
    }
}

extern "C" void kernel_launch(void* const* d_in, const int* in_sizes, int n_in,
                              void* d_out, int out_size, void* d_ws, size_t ws_size,
                              hipStream_t stream) {
    const float* q    = (const float*)d_in[0];
    const float* k    = (const float*)d_in[1];
    const float* v    = (const float*)d_in[2];
    const int*   mask = (const int*)d_in[3];
    float* out = (float*)d_out;
    attend_kernel<<<dim3(512), dim3(512), 0, stream>>>(q, k, v, mask, out);
}

// Round 3
// 75.983 us; speedup vs baseline: 1.5634x; 1.2581x over previous
//
#include <hip/hip_runtime.h>
#include <hip/hip_bf16.h>

#define NSEQ 2048
#define DD   64
#define HH   16
#define QT   128
#define KVB  64
#define NKV  (NSEQ / KVB)
#define LS   72

typedef __attribute__((ext_vector_type(4)))  float f4;
typedef __attribute__((ext_vector_type(16))) float f32x16;
typedef __attribute__((ext_vector_type(8)))  short bf16x8;
typedef __attribute__((ext_vector_type(4)))  unsigned int u32x4;

#define SCL   0.6005612043932249f   /* sqrt(0.25 * log2(e)) */
#define LOG2E 1.4426950408889634f
#define NEGBIG (-1.0e30f)
#define THR   8.0f

#if defined(__has_builtin)
#if __has_builtin(__builtin_amdgcn_exp2f)
#define EXP2F __builtin_amdgcn_exp2f
#endif
#endif
#ifndef EXP2F
#define EXP2F exp2f
#endif

union bfu { u32x4 u; bf16x8 h; };

__device__ __forceinline__ unsigned cvtpk(float lo, float hi) {
    unsigned r;
    asm("v_cvt_pk_bf16_f32 %0, %1, %2" : "=v"(r) : "v"(lo), "v"(hi));
    return r;
}

__global__ __launch_bounds__(256, 2)
void attend_kernel(const float* __restrict__ qg, const float* __restrict__ kg,
                   const float* __restrict__ vg, const int* __restrict__ maskg,
                   float* __restrict__ outg)
{
    __shared__ __align__(16) unsigned short Ks[KVB * LS];  // [j][d] stride 72
    __shared__ __align__(16) unsigned short Vt[DD * LS];   // [d][j] stride 72
    __shared__ __align__(16) float bias_s[KVB];

    const int t    = threadIdx.x;
    const int w    = t >> 6;
    const int lane = t & 63;
    const int c5   = lane & 31;
    const int g2   = lane >> 5;

    // XCD-aware swizzle: 16 q-tiles of one head stay on one XCD
    const int p     = blockIdx.x;
    const int bh    = (p & 7) * 4 + ((p >> 3) >> 4);
    const int qtile = (p >> 3) & 15;
    const int b     = bh >> 4;

    const size_t base = (size_t)bh * NSEQ * DD;
    const float* kp = kg + base;
    const float* vp = vg + base;
    const int*   mp = maskg + b * NSEQ;

    // ---- Q B-fragments (col = query i = c5, k = d = 16ck + 8g2 + 0..7)
    bfu qf[4];
    {
        const float* qp = qg + base + (size_t)(qtile*QT + w*32 + c5) * DD;
        #pragma unroll
        for (int ck = 0; ck < 4; ++ck) {
            f4 a  = *(const f4*)(qp + ck*16 + g2*8);
            f4 bb = *(const f4*)(qp + ck*16 + g2*8 + 4);
            qf[ck].u = (u32x4){ cvtpk(a[0]*SCL,  a[1]*SCL),  cvtpk(a[2]*SCL,  a[3]*SCL),
                                cvtpk(bb[0]*SCL, bb[1]*SCL), cvtpk(bb[2]*SCL, bb[3]*SCL) };
        }
    }

    f32x16 acc0, acc1;
    #pragma unroll
    for (int r = 0; r < 16; ++r) { acc0[r] = 0.f; acc1[r] = 0.f; }
    float m_run = NEGBIG, l_run = 0.f;

    // staging roles: waves 0-1 stage K (+bias), waves 2-3 stage V
    const bool isK = (w < 2);
    const int  jK  = t >> 1;           // K row (valid for t<128)
    const int  dh  = (t & 1) * 32;     // K d-half
    const int  uv  = t & 127;          // V-thread id
    const int  dq  = uv & 15;          // d-quad
    const int  jq  = uv >> 4;          // j-octet

    f4  st[8];
    int mr = 0;

    // ---- prologue: tile 0 -> regs
    if (isK) {
        const float* src = kp + (size_t)jK * DD + dh;
        #pragma unroll
        for (int i2 = 0; i2 < 8; ++i2) st[i2] = ((const f4*)src)[i2];
        mr = mp[jK];
    } else {
        #pragma unroll
        for (int i2 = 0; i2 < 8; ++i2)
            st[i2] = *(const f4*)(vp + (size_t)(jq*8 + i2) * DD + dq*4);
    }

    for (int kt = 0; kt < NKV; ++kt) {
        __syncthreads();
        // ---- stage regs -> LDS
        if (isK) {
            float sq = 0.f;
            #pragma unroll
            for (int i2 = 0; i2 < 8; ++i2)
                sq += st[i2][0]*st[i2][0] + st[i2][1]*st[i2][1]
                    + st[i2][2]*st[i2][2] + st[i2][3]*st[i2][3];
            sq += __shfl_xor(sq, 1);
            if ((t & 1) == 0) bias_s[jK] = (mr > 0) ? NEGBIG : -sq * LOG2E;
            #pragma unroll
            for (int s2 = 0; s2 < 4; ++s2) {
                u32x4 kkw = (u32x4){ cvtpk(st[2*s2][0]*SCL,   st[2*s2][1]*SCL),
                                     cvtpk(st[2*s2][2]*SCL,   st[2*s2][3]*SCL),
                                     cvtpk(st[2*s2+1][0]*SCL, st[2*s2+1][1]*SCL),
                                     cvtpk(st[2*s2+1][2]*SCL, st[2*s2+1][3]*SCL) };
                *(u32x4*)&Ks[jK*LS + dh + 8*s2] = kkw;
            }
        } else {
            #pragma unroll
            for (int cc = 0; cc < 4; ++cc) {
                int d = dq*4 + cc;
                u32x4 tv = (u32x4){ cvtpk(st[0][cc], st[1][cc]),
                                    cvtpk(st[2][cc], st[3][cc]),
                                    cvtpk(st[4][cc], st[5][cc]),
                                    cvtpk(st[6][cc], st[7][cc]) };
                *(u32x4*)&Vt[d*LS + jq*8] = tv;
            }
        }
        __syncthreads();

        // ---- prefetch next tile (hides under compute)
        if (kt + 1 < NKV) {
            const int j0 = (kt + 1) * KVB;
            if (isK) {
                const float* src = kp + (size_t)(j0 + jK) * DD + dh;
                #pragma unroll
                for (int i2 = 0; i2 < 8; ++i2) st[i2] = ((const f4*)src)[i2];
                mr = mp[j0 + jK];
            } else {
                #pragma unroll
                for (int i2 = 0; i2 < 8; ++i2)
                    st[i2] = *(const f4*)(vp + (size_t)(j0 + jq*8 + i2) * DD + dq*4);
            }
        }

        // ---- S^T = K Q^T  (rows j, cols i); bias rides as C-init
        f32x16 s01[2];
        #pragma unroll
        for (int jt = 0; jt < 2; ++jt) {
            f4 b4[4];
            #pragma unroll
            for (int q = 0; q < 4; ++q)
                b4[q] = *(const f4*)&bias_s[32*jt + 8*q + 4*g2];
            f32x16 sc;
            #pragma unroll
            for (int r = 0; r < 16; ++r) sc[r] = b4[r>>2][r&3];
            __builtin_amdgcn_s_setprio(1);
            #pragma unroll
            for (int ck = 0; ck < 4; ++ck) {
                bfu kb;
                kb.u = *(const u32x4*)&Ks[(32*jt + c5)*LS + 16*ck + 8*g2];
                sc = __builtin_amdgcn_mfma_f32_32x32x16_bf16(kb.h, qf[ck].h, sc, 0, 0, 0);
            }
            __builtin_amdgcn_s_setprio(0);
            s01[jt] = sc;
        }

        // ---- online softmax, fully in-register (query i = c5)
        float pmax;
        {
            float mm[8];
            #pragma unroll
            for (int i2 = 0; i2 < 8; ++i2)
                mm[i2] = fmaxf(fmaxf(s01[0][2*i2], s01[0][2*i2+1]),
                               fmaxf(s01[1][2*i2], s01[1][2*i2+1]));
            float ma = fmaxf(fmaxf(mm[0], mm[1]), fmaxf(mm[2], mm[3]));
            float mb = fmaxf(fmaxf(mm[4], mm[5]), fmaxf(mm[6], mm[7]));
            pmax = fmaxf(ma, mb);
        }
        pmax = fmaxf(pmax, __shfl_xor(pmax, 32));
        if (!__all(pmax <= m_run + THR)) {      // defer-max (T13)
            float corr = EXP2F(m_run - pmax);
            m_run = pmax;
            l_run *= corr;
            #pragma unroll
            for (int r = 0; r < 16; ++r) { acc0[r] *= corr; acc1[r] *= corr; }
        }
        f32x16 p0, p1;
        #pragma unroll
        for (int r = 0; r < 16; ++r) p0[r] = EXP2F(s01[0][r] - m_run);
        #pragma unroll
        for (int r = 0; r < 16; ++r) p1[r] = EXP2F(s01[1][r] - m_run);
        float lsum;
        {
            float ss[8];
            #pragma unroll
            for (int i2 = 0; i2 < 8; ++i2)
                ss[i2] = (p0[2*i2] + p0[2*i2+1]) + (p1[2*i2] + p1[2*i2+1]);
            lsum = ((ss[0]+ss[1]) + (ss[2]+ss[3])) + ((ss[4]+ss[5]) + (ss[6]+ss[7]));
        }
        lsum += __shfl_xor(lsum, 32);
        l_run += lsum;

        // ---- pack P to bf16 pairs, build PV B-frags via xor32 exchange
        unsigned W0[8], W1[8];
        #pragma unroll
        for (int m = 0; m < 8; ++m) {
            W0[m] = cvtpk(p0[2*m], p0[2*m+1]);
            W1[m] = cvtpk(p1[2*m], p1[2*m+1]);
        }
        const bool hi = (g2 != 0);
        __builtin_amdgcn_s_setprio(1);
        #pragma unroll
        for (int ck = 0; ck < 4; ++ck) {
            const int bse = 4*(ck&1);
            unsigned wA0 = (ck>>1) ? W1[bse]   : W0[bse];
            unsigned wA1 = (ck>>1) ? W1[bse+1] : W0[bse+1];
            unsigned wB0 = (ck>>1) ? W1[bse+2] : W0[bse+2];
            unsigned wB1 = (ck>>1) ? W1[bse+3] : W0[bse+3];
            unsigned v  = hi ? wA0 : wB0;
            unsigned v2 = hi ? wA1 : wB1;
            unsigned x  = (unsigned)__shfl_xor((int)v, 32);
            unsigned x2 = (unsigned)__shfl_xor((int)v2, 32);
            bfu pb;
            pb.u = (u32x4){ hi ? x : wA0, hi ? x2 : wA1, hi ? wB0 : x, hi ? wB1 : x2 };
            bfu va0, va1;
            va0.u = *(const u32x4*)&Vt[(     c5)*LS + 16*ck + 8*g2];
            va1.u = *(const u32x4*)&Vt[(32 + c5)*LS + 16*ck + 8*g2];
            acc0 = __builtin_amdgcn_mfma_f32_32x32x16_bf16(va0.h, pb.h, acc0, 0, 0, 0);
            acc1 = __builtin_amdgcn_mfma_f32_32x32x16_bf16(va1.h, pb.h, acc1, 0, 0, 0);
        }
        __builtin_amdgcn_s_setprio(0);
    }

    // ---- epilogue: O^T lane-local normalize, f4 stores
    float inv = 1.0f / l_run;
    float* op = outg + base + (size_t)(qtile*QT + w*32 + c5) * DD;
    #pragma unroll
    for (int dt = 0; dt < 2; ++dt) {
        const f32x16 A = dt ? acc1 : acc0;
        #pragma unroll
        for (int q = 0; q < 4; ++q) {
            f4 o = { A[4*q]*inv, A[4*q+1]*inv, A[4*q+2]*inv, A[4*q+3]*inv };
            *(f4*)(op + 32*dt + 8*q + 4*g2) = o;
        }
    }
}

extern "C" void kernel_launch(void* const* d_in, const int* in_sizes, int n_in,
                              void* d_out, int out_size, void* d_ws, size_t ws_size,
                              hipStream_t stream) {
    const float* q    = (const float*)d_in[0];
    const float* k    = (const float*)d_in[1];
    const float* v    = (const float*)d_in[2];
    const int*   mask = (const int*)d_in[3];
    float* out = (float*)d_out;
    attend_kernel<<<dim3(512), dim3(256), 0, stream>>>(q, k, v, mask, out);
}

// Round 4
// 70.546 us; speedup vs baseline: 1.6838x; 1.0771x over previous
//
#include <hip/hip_runtime.h>
#include <hip/hip_bf16.h>

#define NSEQ 2048
#define DD   64
#define HH   16
#define QT   128
#define KVB  64
#define NKV  (NSEQ / KVB)

typedef __attribute__((ext_vector_type(4)))  float f4;
typedef __attribute__((ext_vector_type(16))) float f32x16;
typedef __attribute__((ext_vector_type(8)))  short bf16x8;
typedef __attribute__((ext_vector_type(4)))  unsigned int u32x4;

#define SCL   0.6005612043932249f   /* sqrt(0.25 * log2(e)) */
#define LOG2E 1.4426950408889634f
#define NEGBIG (-1.0e30f)
#define THR   8.0f

/* element offset of 16B-quad `q` in row `row` of a 64-wide bf16 tile,
   XOR-swizzled so column-slice b128 reads are bank-conflict-free */
#define SWZ(row, q) (((row) << 6) + ((((q) ^ ((row) & 7))) << 3))

#if defined(__has_builtin)
#if __has_builtin(__builtin_amdgcn_exp2f)
#define EXP2F __builtin_amdgcn_exp2f
#endif
#endif
#ifndef EXP2F
#define EXP2F exp2f
#endif

union bfu { u32x4 u; bf16x8 h; };

__device__ __forceinline__ unsigned cvtpk(float lo, float hi) {
    unsigned r;
    asm("v_cvt_pk_bf16_f32 %0, %1, %2" : "=v"(r) : "v"(lo), "v"(hi));
    return r;
}

__global__ __launch_bounds__(256, 2)
void attend_kernel(const float* __restrict__ qg, const float* __restrict__ kg,
                   const float* __restrict__ vg, const int* __restrict__ maskg,
                   float* __restrict__ outg)
{
    __shared__ __align__(16) unsigned short Ks[2][KVB * DD];  // [j][d] swizzled
    __shared__ __align__(16) unsigned short Vt[2][DD * KVB];  // [d][j] swizzled
    __shared__ __align__(16) float bias_s[2][KVB];

    const int t    = threadIdx.x;
    const int w    = t >> 6;
    const int lane = t & 63;
    const int c5   = lane & 31;
    const int g2   = lane >> 5;

    // XCD-aware swizzle: 16 q-tiles of one head stay on one XCD
    const int p     = blockIdx.x;
    const int bh    = (p & 7) * 4 + ((p >> 3) >> 4);
    const int qtile = (p >> 3) & 15;
    const int b     = bh >> 4;

    const size_t base = (size_t)bh * NSEQ * DD;
    const float* kp = kg + base;
    const float* vp = vg + base;
    const int*   mp = maskg + b * NSEQ;

    // ---- Q B-fragments (col = query i = c5, k = d = 16ck + 8g2 + 0..7)
    bfu qf[4];
    {
        const float* qp = qg + base + (size_t)(qtile*QT + w*32 + c5) * DD;
        #pragma unroll
        for (int ck = 0; ck < 4; ++ck) {
            f4 a  = *(const f4*)(qp + ck*16 + g2*8);
            f4 bb = *(const f4*)(qp + ck*16 + g2*8 + 4);
            qf[ck].u = (u32x4){ cvtpk(a[0]*SCL,  a[1]*SCL),  cvtpk(a[2]*SCL,  a[3]*SCL),
                                cvtpk(bb[0]*SCL, bb[1]*SCL), cvtpk(bb[2]*SCL, bb[3]*SCL) };
        }
    }

    f32x16 acc0, acc1;
    #pragma unroll
    for (int r = 0; r < 16; ++r) { acc0[r] = 0.f; acc1[r] = 0.f; }
    float m_run = NEGBIG, l_run = 0.f;

    // staging roles: waves 0-1 stage K (+bias), waves 2-3 stage V
    const bool isK = (w < 2);
    const int  jK  = t >> 1;           // K row (threads < 128)
    const int  kq0 = (t & 1) * 4;      // starting 16B-quad (d-half)
    const int  uv  = t & 127;
    const int  dq  = uv & 15;          // V d-quad
    const int  jq  = uv >> 4;          // V j-octet (= col quad)

    f4  st[8];
    int mr = 0;

    auto loadTile = [&](int kt2) {
        const int j0 = kt2 * KVB;
        if (isK) {
            const float* src = kp + (size_t)(j0 + jK) * DD + kq0 * 8;
            #pragma unroll
            for (int i2 = 0; i2 < 8; ++i2) st[i2] = ((const f4*)src)[i2];
            mr = mp[j0 + jK];
        } else {
            #pragma unroll
            for (int i2 = 0; i2 < 8; ++i2)
                st[i2] = *(const f4*)(vp + (size_t)(j0 + jq*8 + i2) * DD + dq*4);
        }
    };

    auto stageTile = [&](int bsel) {
        if (isK) {
            float sq = 0.f;
            #pragma unroll
            for (int i2 = 0; i2 < 8; ++i2)
                sq += st[i2][0]*st[i2][0] + st[i2][1]*st[i2][1]
                    + st[i2][2]*st[i2][2] + st[i2][3]*st[i2][3];
            sq += __shfl_xor(sq, 1);
            if ((t & 1) == 0) bias_s[bsel][jK] = (mr > 0) ? NEGBIG : -sq * LOG2E;
            #pragma unroll
            for (int s2 = 0; s2 < 4; ++s2) {
                u32x4 kkw = (u32x4){ cvtpk(st[2*s2][0]*SCL,   st[2*s2][1]*SCL),
                                     cvtpk(st[2*s2][2]*SCL,   st[2*s2][3]*SCL),
                                     cvtpk(st[2*s2+1][0]*SCL, st[2*s2+1][1]*SCL),
                                     cvtpk(st[2*s2+1][2]*SCL, st[2*s2+1][3]*SCL) };
                *(u32x4*)&Ks[bsel][SWZ(jK, kq0 + s2)] = kkw;
            }
        } else {
            #pragma unroll
            for (int cc = 0; cc < 4; ++cc) {
                int d = dq*4 + cc;
                u32x4 tv = (u32x4){ cvtpk(st[0][cc], st[1][cc]),
                                    cvtpk(st[2][cc], st[3][cc]),
                                    cvtpk(st[4][cc], st[5][cc]),
                                    cvtpk(st[6][cc], st[7][cc]) };
                *(u32x4*)&Vt[bsel][SWZ(d, jq)] = tv;
            }
        }
    };

    // ---- prologue: tile0 -> LDS[0]; tile1 -> regs
    loadTile(0);
    stageTile(0);
    loadTile(1);
    __syncthreads();

    int cur = 0;
    for (int kt = 0; kt < NKV; ++kt) {
        // stage tile kt+1 into the other buffer (overlaps compute below)
        if (kt + 1 < NKV) stageTile(cur ^ 1);
        // prefetch tile kt+2 (global -> regs; lands during compute)
        if (kt + 2 < NKV) loadTile(kt + 2);

        // ---- S^T = K Q^T  (rows j, cols i); bias rides as C-init
        f32x16 s01[2];
        #pragma unroll
        for (int jt = 0; jt < 2; ++jt) {
            f4 b4[4];
            #pragma unroll
            for (int q = 0; q < 4; ++q)
                b4[q] = *(const f4*)&bias_s[cur][32*jt + 8*q + 4*g2];
            f32x16 sc;
            #pragma unroll
            for (int r = 0; r < 16; ++r) sc[r] = b4[r>>2][r&3];
            __builtin_amdgcn_s_setprio(1);
            #pragma unroll
            for (int ck = 0; ck < 4; ++ck) {
                bfu kb;
                kb.u = *(const u32x4*)&Ks[cur][SWZ(32*jt + c5, 2*ck + g2)];
                sc = __builtin_amdgcn_mfma_f32_32x32x16_bf16(kb.h, qf[ck].h, sc, 0, 0, 0);
            }
            __builtin_amdgcn_s_setprio(0);
            s01[jt] = sc;
        }

        // ---- online softmax, fully in-register (query i = c5)
        float pmax;
        {
            float mm[8];
            #pragma unroll
            for (int i2 = 0; i2 < 8; ++i2)
                mm[i2] = fmaxf(fmaxf(s01[0][2*i2], s01[0][2*i2+1]),
                               fmaxf(s01[1][2*i2], s01[1][2*i2+1]));
            float ma = fmaxf(fmaxf(mm[0], mm[1]), fmaxf(mm[2], mm[3]));
            float mb = fmaxf(fmaxf(mm[4], mm[5]), fmaxf(mm[6], mm[7]));
            pmax = fmaxf(ma, mb);
        }
        pmax = fmaxf(pmax, __shfl_xor(pmax, 32));
        if (!__all(pmax <= m_run + THR)) {      // defer-max (T13)
            float corr = EXP2F(m_run - pmax);
            m_run = pmax;
            l_run *= corr;
            #pragma unroll
            for (int r = 0; r < 16; ++r) { acc0[r] *= corr; acc1[r] *= corr; }
        }
        f32x16 p0, p1;
        #pragma unroll
        for (int r = 0; r < 16; ++r) p0[r] = EXP2F(s01[0][r] - m_run);
        #pragma unroll
        for (int r = 0; r < 16; ++r) p1[r] = EXP2F(s01[1][r] - m_run);
        float lsum;
        {
            float ss[8];
            #pragma unroll
            for (int i2 = 0; i2 < 8; ++i2)
                ss[i2] = (p0[2*i2] + p0[2*i2+1]) + (p1[2*i2] + p1[2*i2+1]);
            lsum = ((ss[0]+ss[1]) + (ss[2]+ss[3])) + ((ss[4]+ss[5]) + (ss[6]+ss[7]));
        }
        lsum += __shfl_xor(lsum, 32);
        l_run += lsum;

        // ---- pack P to bf16 pairs, build PV B-frags via xor32 exchange
        unsigned W0[8], W1[8];
        #pragma unroll
        for (int m = 0; m < 8; ++m) {
            W0[m] = cvtpk(p0[2*m], p0[2*m+1]);
            W1[m] = cvtpk(p1[2*m], p1[2*m+1]);
        }
        const bool hi = (g2 != 0);
        __builtin_amdgcn_s_setprio(1);
        #pragma unroll
        for (int ck = 0; ck < 4; ++ck) {
            const int bse = 4*(ck&1);
            unsigned wA0 = (ck>>1) ? W1[bse]   : W0[bse];
            unsigned wA1 = (ck>>1) ? W1[bse+1] : W0[bse+1];
            unsigned wB0 = (ck>>1) ? W1[bse+2] : W0[bse+2];
            unsigned wB1 = (ck>>1) ? W1[bse+3] : W0[bse+3];
            unsigned v  = hi ? wA0 : wB0;
            unsigned v2 = hi ? wA1 : wB1;
            unsigned x  = (unsigned)__shfl_xor((int)v, 32);
            unsigned x2 = (unsigned)__shfl_xor((int)v2, 32);
            bfu pb;
            pb.u = (u32x4){ hi ? x : wA0, hi ? x2 : wA1, hi ? wB0 : x, hi ? wB1 : x2 };
            bfu va0, va1;
            va0.u = *(const u32x4*)&Vt[cur][SWZ(     c5, 2*ck + g2)];
            va1.u = *(const u32x4*)&Vt[cur][SWZ(32 + c5, 2*ck + g2)];
            acc0 = __builtin_amdgcn_mfma_f32_32x32x16_bf16(va0.h, pb.h, acc0, 0, 0, 0);
            acc1 = __builtin_amdgcn_mfma_f32_32x32x16_bf16(va1.h, pb.h, acc1, 0, 0, 0);
        }
        __builtin_amdgcn_s_setprio(0);

        __syncthreads();
        cur ^= 1;
    }

    // ---- epilogue: O^T lane-local normalize, f4 stores
    float inv = 1.0f / l_run;
    float* op = outg + base + (size_t)(qtile*QT + w*32 + c5) * DD;
    #pragma unroll
    for (int dt = 0; dt < 2; ++dt) {
        const f32x16 A = dt ? acc1 : acc0;
        #pragma unroll
        for (int q = 0; q < 4; ++q) {
            f4 o = { A[4*q]*inv, A[4*q+1]*inv, A[4*q+2]*inv, A[4*q+3]*inv };
            *(f4*)(op + 32*dt + 8*q + 4*g2) = o;
        }
    }
}

extern "C" void kernel_launch(void* const* d_in, const int* in_sizes, int n_in,
                              void* d_out, int out_size, void* d_ws, size_t ws_size,
                              hipStream_t stream) {
    const float* q    = (const float*)d_in[0];
    const float* k    = (const float*)d_in[1];
    const float* v    = (const float*)d_in[2];
    const int*   mask = (const int*)d_in[3];
    float* out = (float*)d_out;
    attend_kernel<<<dim3(512), dim3(256), 0, stream>>>(q, k, v, mask, out);
}